// Round 7
// baseline (136.309 us; speedup 1.0000x reference)
//
#include <hip/hip_runtime.h>
#include <hip/hip_fp16.h>

#define BS 2
#define NS 50000
#define CCH 32
#define RR 128
#define SS 8

typedef float v2f __attribute__((ext_vector_type(2)));
typedef _Float16 h2 __attribute__((ext_vector_type(2)));

#if __has_builtin(__builtin_amdgcn_fdot2)
#define HAVE_DOT2 1
#else
#define HAVE_DOT2 0
#endif

// ws layout (pair-replicated fp16 planes):
//   tp : BS*3*RR*RR blocks of 128 B:
//        block (b,pl,y,x) holds channels c=0..31 interleaved {col x, col x+1}:
//        uint32 #c = half(src[c][y][x]) | half(src[c][y][min(x+1,127)])<<16
//   Wc : 1024 floats  (W_v @ W_out)
//   bvw: 32 floats    (b_v @ W_out)

__device__ __forceinline__ unsigned pk_rn(float a, float b) {
    unsigned h0 = __half_as_ushort(__float2half(a));
    unsigned h1 = __half_as_ushort(__float2half(b));
    return h0 | (h1 << 16);
}

__global__ __launch_bounds__(256)
void prep(const float* __restrict__ cxz,
          const float* __restrict__ cxy,
          const float* __restrict__ cyz,
          const float* __restrict__ Wv, const float* __restrict__ bv,
          const float* __restrict__ Wout,
          unsigned* __restrict__ tp, float* __restrict__ Wc,
          float* __restrict__ bvw) {
    __shared__ float lds[32 * 129];
    int tid = threadIdx.x;
    int row = blockIdx.x;
    if (row < BS * 3 * RR) {
        int y  = row & 127;
        int pl = (row >> 7) % 3;
        int b  = row / 384;
        const float* src = (pl == 0) ? cxz : ((pl == 1) ? cxy : cyz);
        const float* sp = src + (((size_t)(b * CCH)) << 14) + (y << 7);
        int c = tid >> 3, xq = tid & 7;
        const float4* s4 = (const float4*)(sp + ((size_t)c << 14));
#pragma unroll
        for (int k = 0; k < 4; ++k) {
            float4 v = s4[xq + 8 * k];
            int x = (xq + 8 * k) << 2;
            lds[c * 129 + x + 0] = v.x;
            lds[c * 129 + x + 1] = v.y;
            lds[c * 129 + x + 2] = v.z;
            lds[c * 129 + x + 3] = v.w;
        }
        __syncthreads();
        uint4* dst = (uint4*)(tp + ((size_t)row << 12));
#pragma unroll
        for (int i = 0; i < 4; ++i) {
            int j = tid + 256 * i;          // uint4 index 0..1023
            int x  = j >> 3;
            int c0 = (j & 7) << 2;          // channels c0..c0+3 at column x
            int x1 = min(x + 1, 127);
            uint4 o;
            o.x = pk_rn(lds[(c0 + 0) * 129 + x], lds[(c0 + 0) * 129 + x1]);
            o.y = pk_rn(lds[(c0 + 1) * 129 + x], lds[(c0 + 1) * 129 + x1]);
            o.z = pk_rn(lds[(c0 + 2) * 129 + x], lds[(c0 + 2) * 129 + x1]);
            o.w = pk_rn(lds[(c0 + 3) * 129 + x], lds[(c0 + 3) * 129 + x1]);
            dst[j] = o;
        }
    } else {
        int t = (row - BS * 3 * RR) * 256 + tid;    // 0..1023
        int c = t >> 5, j = t & 31;
        float acc = 0.f;
#pragma unroll
        for (int k = 0; k < 32; ++k) acc += Wv[c * 32 + k] * Wout[k * 32 + j];
        Wc[t] = acc;
        if (t < 32) {
            float a2 = 0.f;
#pragma unroll
            for (int k = 0; k < 32; ++k) a2 += bv[k] * Wout[k * 32 + t];
            bvw[t] = a2;
        }
    }
}

// ---- main kernel: 8 lanes/query, lane owns channels 4l..4l+3.
// TWO queries per thread (q and q+32): two independent dependency chains per
// thread double outstanding loads in every phase (latency-bound fix).
// Tap addressing: wave-uniform base + 32-bit byte offsets.
// Byte offsets: plane stride 1<<21, y stride 1<<14, x stride 1<<7.

struct f4 { v2f lo, hi; };   // 4 channels

struct Coord {
    int o0, o1, o2, o3, o4, o5;
    float wc0, wc1, wr1, wr2;
};

__device__ __forceinline__ Coord coord(float p0, float p1, float p2) {
    Coord c;
    float x0c = fminf(fmaxf(p0, 0.f), 1.f) * 127.f;
    int i0 = min((int)x0c, 126);
    c.wc0 = x0c - (float)i0;
    float x1c = fminf(fmaxf(p1, 0.f), 1.f) * 127.f;
    int i1 = min((int)x1c, 126);
    c.wc1 = x1c - (float)i1;
    float f1 = floorf(x1c);
    int r10 = (int)f1, r11 = min(r10 + 1, 127);
    c.wr1 = x1c - f1;
    float x2c = fminf(fmaxf(p2, 0.f), 1.f) * 127.f;
    float f2 = floorf(x2c);
    int r20 = (int)f2, r21 = min(r20 + 1, 127);
    c.wr2 = x2c - f2;
    int c0 = i0 << 7, c1 = i1 << 7;
    c.o0 = (r20 << 14) + c0;
    c.o1 = (r21 << 14) + c0;
    c.o2 = (1 << 21) + (r10 << 14) + c0;
    c.o3 = (1 << 21) + (r11 << 14) + c0;
    c.o4 = (2 << 21) + (r20 << 14) + c1;
    c.o5 = (2 << 21) + (r21 << 14) + c1;
    return c;
}

__device__ __forceinline__ uint4 ldtap(const char* __restrict__ tpb, int off) {
    return *(const uint4*)(tpb + off);
}

struct SampB { uint4 u[6]; };   // in-flight tap data (24 VGPR)

__device__ __forceinline__ unsigned pack2(float a, float b) {
#if HAVE_DOT2
    return __builtin_bit_cast(unsigned, __builtin_amdgcn_cvt_pkrtz(a, b));
#else
    __half2 h = __floats2half2_rn(a, b);
    return __builtin_bit_cast(unsigned, h);
#endif
}

#if HAVE_DOT2
__device__ __forceinline__ void eval_row(f4& acc, uint4 u, h2 w) {
    acc.lo.x = __builtin_amdgcn_fdot2(__builtin_bit_cast(h2, u.x), w, acc.lo.x, false);
    acc.lo.y = __builtin_amdgcn_fdot2(__builtin_bit_cast(h2, u.y), w, acc.lo.y, false);
    acc.hi.x = __builtin_amdgcn_fdot2(__builtin_bit_cast(h2, u.z), w, acc.hi.x, false);
    acc.hi.y = __builtin_amdgcn_fdot2(__builtin_bit_cast(h2, u.w), w, acc.hi.y, false);
}

__device__ __forceinline__ void eval_plane(f4& acc, uint4 ua, uint4 ub,
                                           float wx, float wy) {
    float wB1 = wx * wy;          // (x1,y1)
    float wB0 = wx - wB1;         // (x1,y0)
    float wA1 = wy - wB1;         // (x0,y1)
    float wA0 = 1.f - wx - wA1;   // (x0,y0)
    h2 w0 = __builtin_bit_cast(h2, __builtin_amdgcn_cvt_pkrtz(wA0, wB0));
    h2 w1 = __builtin_bit_cast(h2, __builtin_amdgcn_cvt_pkrtz(wA1, wB1));
    eval_row(acc, ua, w0);
    eval_row(acc, ub, w1);
}

__device__ __forceinline__ void eval_rowp(f4& acc, uint4 u, unsigned pw) {
    eval_row(acc, u, __builtin_bit_cast(h2, pw));
}

__device__ __forceinline__ void dot2_4(f4& acc, uint4 wv, unsigned pw) {
    h2 w = __builtin_bit_cast(h2, pw);
    acc.lo.x = __builtin_amdgcn_fdot2(__builtin_bit_cast(h2, wv.x), w, acc.lo.x, false);
    acc.lo.y = __builtin_amdgcn_fdot2(__builtin_bit_cast(h2, wv.y), w, acc.lo.y, false);
    acc.hi.x = __builtin_amdgcn_fdot2(__builtin_bit_cast(h2, wv.z), w, acc.hi.x, false);
    acc.hi.y = __builtin_amdgcn_fdot2(__builtin_bit_cast(h2, wv.w), w, acc.hi.y, false);
}
#else
__device__ __forceinline__ void eval_row(f4& acc, uint4 u, float wA, float wB) {
    __half2 h0 = __builtin_bit_cast(__half2, u.x);
    __half2 h1 = __builtin_bit_cast(__half2, u.y);
    __half2 h2_ = __builtin_bit_cast(__half2, u.z);
    __half2 h3 = __builtin_bit_cast(__half2, u.w);
    acc.lo.x = fmaf(__half2float(h0.y), wB, fmaf(__half2float(h0.x), wA, acc.lo.x));
    acc.lo.y = fmaf(__half2float(h1.y), wB, fmaf(__half2float(h1.x), wA, acc.lo.y));
    acc.hi.x = fmaf(__half2float(h2_.y), wB, fmaf(__half2float(h2_.x), wA, acc.hi.x));
    acc.hi.y = fmaf(__half2float(h3.y), wB, fmaf(__half2float(h3.x), wA, acc.hi.y));
}

__device__ __forceinline__ void eval_plane(f4& acc, uint4 ua, uint4 ub,
                                           float wx, float wy) {
    float wB1 = wx * wy;
    float wB0 = wx - wB1;
    float wA1 = wy - wB1;
    float wA0 = 1.f - wx - wA1;
    eval_row(acc, ua, wA0, wB0);
    eval_row(acc, ub, wA1, wB1);
}

__device__ __forceinline__ void eval_rowp(f4& acc, uint4 u, unsigned pw) {
    __half2 hw = __builtin_bit_cast(__half2, pw);
    eval_row(acc, u, __half2float(hw.x), __half2float(hw.y));
}

__device__ __forceinline__ void dot2_4(f4& acc, uint4 wv, unsigned pw) {
    __half2 hw = __builtin_bit_cast(__half2, pw);
    float a0 = __half2float(hw.x), a1 = __half2float(hw.y);
    __half2 w0 = __builtin_bit_cast(__half2, wv.x);
    __half2 w1 = __builtin_bit_cast(__half2, wv.y);
    __half2 w2_ = __builtin_bit_cast(__half2, wv.z);
    __half2 w3 = __builtin_bit_cast(__half2, wv.w);
    acc.lo.x = fmaf(__half2float(w0.y), a1, fmaf(__half2float(w0.x), a0, acc.lo.x));
    acc.lo.y = fmaf(__half2float(w1.y), a1, fmaf(__half2float(w1.x), a0, acc.lo.y));
    acc.hi.x = fmaf(__half2float(w2_.y), a1, fmaf(__half2float(w2_.x), a0, acc.hi.x));
    acc.hi.y = fmaf(__half2float(w3.y), a1, fmaf(__half2float(w3.x), a0, acc.hi.y));
}
#endif

// element idx (0..3 within lane) of f4; compile-time idx.
#define GETE(v, idx) (((idx) & 2) ? (((idx) & 1) ? (v).hi.y : (v).hi.x) \
                                  : (((idx) & 1) ? (v).lo.y : (v).lo.x))
// broadcast channel idx (0..31) across the 8-lane query group (base = tid & 56).
#define GETC(v, idx) __shfl(GETE(v, idx), base | ((idx) >> 2), 64)

// per-query state carried through the kernel (explicit, statically indexed)
struct Q {
    float p0, p1, p2;
    f4 feat, cat, wa;
    Coord my;
    unsigned m0, m1, m2, m3, m4, m5;
    float wsum;
};

__global__ __launch_bounds__(256)
void eda_main(const float* __restrict__ qp, const unsigned* __restrict__ tp,
              const float* __restrict__ Woff, const float* __restrict__ boff,
              const float* __restrict__ Ww, const float* __restrict__ bw,
              const float* __restrict__ Wc, const float* __restrict__ bvw,
              const float* __restrict__ bout, float* __restrict__ out) {
    // sWcat: COLUMN-PERMUTED, F32 (offsets are gradient-amplified; fp16 failed R4):
    //   col 4l+e = (e<3) ? W_off col (3l+e) : W_w col l
    __shared__ float    sWcat[32][32];
    __shared__ unsigned sWc2h[16][32];  // f16-pair packed Wc
    __shared__ float sbcat[32];
    __shared__ float sbvw[32];
    __shared__ float sbout[32];

    int tid = threadIdx.x;
    int lane = tid & 7;
    int lane16 = lane << 4;
    int base = tid & 56;                          // query-group base within wave
    int b  = blockIdx.x & 1;                      // XCD-parity batch split
    int qiA = (blockIdx.x >> 1) * 64 + (tid >> 3);
    int qiB = qiA + 32;
    int qqA = min(qiA, NS - 1);
    int qqB = min(qiB, NS - 1);

    const float* pA = qp + ((size_t)b * NS + qqA) * 3;
    const float* pB = qp + ((size_t)b * NS + qqB) * 3;
    Q A, B;
    A.p0 = pA[0]; A.p1 = pA[1]; A.p2 = pA[2];
    B.p0 = pB[0]; B.p1 = pB[1]; B.p2 = pB[2];

    // wave-uniform plane base (batch select); taps use 32-bit byte offsets
    const char* tpb = (const char*)tp + ((size_t)(b * 3) << 21);

    // ---- issue BOTH queries' feature taps early (12 loads in flight
    //      during weight staging) ----
    Coord fcA = coord(A.p0, A.p1, A.p2);
    Coord fcB = coord(B.p0, B.p1, B.p2);
    SampB fsA, fsB;
    fsA.u[0] = ldtap(tpb, fcA.o0 + lane16); fsA.u[1] = ldtap(tpb, fcA.o1 + lane16);
    fsA.u[2] = ldtap(tpb, fcA.o2 + lane16); fsA.u[3] = ldtap(tpb, fcA.o3 + lane16);
    fsA.u[4] = ldtap(tpb, fcA.o4 + lane16); fsA.u[5] = ldtap(tpb, fcA.o5 + lane16);
    fsB.u[0] = ldtap(tpb, fcB.o0 + lane16); fsB.u[1] = ldtap(tpb, fcB.o1 + lane16);
    fsB.u[2] = ldtap(tpb, fcB.o2 + lane16); fsB.u[3] = ldtap(tpb, fcB.o3 + lane16);
    fsB.u[4] = ldtap(tpb, fcB.o4 + lane16); fsB.u[5] = ldtap(tpb, fcB.o5 + lane16);

    for (int i = tid; i < 1024; i += 256) {
        int k = i >> 5, j = i & 31, l2 = j >> 2, e = j & 3;
        sWcat[k][j] = (e < 3) ? Woff[k * 24 + 3 * l2 + e] : Ww[k * 8 + l2];
    }
    {
        int k2 = tid >> 5, j = tid & 31;
        sWc2h[k2][j]     = pk_rn(Wc[k2 * 64 + j],        Wc[k2 * 64 + 32 + j]);
        sWc2h[k2 + 8][j] = pk_rn(Wc[(k2 + 8) * 64 + j],  Wc[(k2 + 8) * 64 + 32 + j]);
    }
    if (tid < 32) {
        int l2 = tid >> 2, e = tid & 3;
        sbcat[tid] = (e < 3) ? boff[3 * l2 + e] : bw[l2];
        sbvw[tid]  = bvw[tid];
        sbout[tid] = bout[tid];
    }
    __syncthreads();

    // ---- features (A then B; independent chains interleave) ----
    A.feat.lo = (v2f){0.f, 0.f}; A.feat.hi = (v2f){0.f, 0.f};
    eval_plane(A.feat, fsA.u[0], fsA.u[1], fcA.wc0, fcA.wr2);   // XZ
    eval_plane(A.feat, fsA.u[2], fsA.u[3], fcA.wc0, fcA.wr1);   // XY
    eval_plane(A.feat, fsA.u[4], fsA.u[5], fcA.wc1, fcA.wr2);   // YZ
    B.feat.lo = (v2f){0.f, 0.f}; B.feat.hi = (v2f){0.f, 0.f};
    eval_plane(B.feat, fsB.u[0], fsB.u[1], fcB.wc0, fcB.wr2);
    eval_plane(B.feat, fsB.u[2], fsB.u[3], fcB.wc0, fcB.wr1);
    eval_plane(B.feat, fsB.u[4], fsB.u[5], fcB.wc1, fcB.wr2);

    // ---- cat = feature @ [W_off | W_w] (permuted cols, F32) + bias ----
    A.cat.lo.x = sbcat[(lane << 2) + 0]; A.cat.lo.y = sbcat[(lane << 2) + 1];
    A.cat.hi.x = sbcat[(lane << 2) + 2]; A.cat.hi.y = sbcat[(lane << 2) + 3];
    B.cat = A.cat;
#pragma unroll
    for (int k = 0; k < 32; ++k) {
        float fA = GETC(A.feat, k);
        float fB = GETC(B.feat, k);
        const v2f* wp = (const v2f*)&sWcat[k][lane << 2];
        v2f w0 = wp[0], w1 = wp[1];
        v2f fa2 = {fA, fA};
        v2f fb2 = {fB, fB};
        A.cat.lo = __builtin_elementwise_fma(fa2, w0, A.cat.lo);
        A.cat.hi = __builtin_elementwise_fma(fa2, w1, A.cat.hi);
        B.cat.lo = __builtin_elementwise_fma(fb2, w0, B.cat.lo);
        B.cat.hi = __builtin_elementwise_fma(fb2, w1, B.cat.hi);
    }

    // ---- per-lane precompute for MY sample (s = lane), both queries ----
    A.my = coord(A.p0 + A.cat.lo.x, A.p1 + A.cat.lo.y, A.p2 + A.cat.hi.x);
    B.my = coord(B.p0 + B.cat.lo.x, B.p1 + B.cat.lo.y, B.p2 + B.cat.hi.x);
    {
        float wt = A.cat.hi.y;
        { float wB1 = A.my.wc0 * A.my.wr2, wB0 = A.my.wc0 - wB1, wA1 = A.my.wr2 - wB1, wA0 = 1.f - A.my.wc0 - wA1;
          A.m0 = pack2(wA0 * wt, wB0 * wt); A.m1 = pack2(wA1 * wt, wB1 * wt); }
        { float wB1 = A.my.wc0 * A.my.wr1, wB0 = A.my.wc0 - wB1, wA1 = A.my.wr1 - wB1, wA0 = 1.f - A.my.wc0 - wA1;
          A.m2 = pack2(wA0 * wt, wB0 * wt); A.m3 = pack2(wA1 * wt, wB1 * wt); }
        { float wB1 = A.my.wc1 * A.my.wr2, wB0 = A.my.wc1 - wB1, wA1 = A.my.wr2 - wB1, wA0 = 1.f - A.my.wc1 - wA1;
          A.m4 = pack2(wA0 * wt, wB0 * wt); A.m5 = pack2(wA1 * wt, wB1 * wt); }
        A.wsum = wt;
        A.wsum += __shfl_xor(A.wsum, 1, 64);
        A.wsum += __shfl_xor(A.wsum, 2, 64);
        A.wsum += __shfl_xor(A.wsum, 4, 64);
    }
    {
        float wt = B.cat.hi.y;
        { float wB1 = B.my.wc0 * B.my.wr2, wB0 = B.my.wc0 - wB1, wA1 = B.my.wr2 - wB1, wA0 = 1.f - B.my.wc0 - wA1;
          B.m0 = pack2(wA0 * wt, wB0 * wt); B.m1 = pack2(wA1 * wt, wB1 * wt); }
        { float wB1 = B.my.wc0 * B.my.wr1, wB0 = B.my.wc0 - wB1, wA1 = B.my.wr1 - wB1, wA0 = 1.f - B.my.wc0 - wA1;
          B.m2 = pack2(wA0 * wt, wB0 * wt); B.m3 = pack2(wA1 * wt, wB1 * wt); }
        { float wB1 = B.my.wc1 * B.my.wr2, wB0 = B.my.wc1 - wB1, wA1 = B.my.wr2 - wB1, wA0 = 1.f - B.my.wc1 - wA1;
          B.m4 = pack2(wA0 * wt, wB0 * wt); B.m5 = pack2(wA1 * wt, wB1 * wt); }
        B.wsum = wt;
        B.wsum += __shfl_xor(B.wsum, 1, 64);
        B.wsum += __shfl_xor(B.wsum, 2, 64);
        B.wsum += __shfl_xor(B.wsum, 4, 64);
    }

    // ---- s-loop: dual-query depth-1 pipeline (12 tap loads in flight) ----
    A.wa.lo = (v2f){0.f, 0.f}; A.wa.hi = (v2f){0.f, 0.f};
    B.wa = A.wa;
    SampB curA, curB, nxtA, nxtB;
    {
        int src = base;        // s = 0
        curA.u[0] = ldtap(tpb, __shfl(A.my.o0, src, 64) + lane16);
        curA.u[1] = ldtap(tpb, __shfl(A.my.o1, src, 64) + lane16);
        curA.u[2] = ldtap(tpb, __shfl(A.my.o2, src, 64) + lane16);
        curA.u[3] = ldtap(tpb, __shfl(A.my.o3, src, 64) + lane16);
        curA.u[4] = ldtap(tpb, __shfl(A.my.o4, src, 64) + lane16);
        curA.u[5] = ldtap(tpb, __shfl(A.my.o5, src, 64) + lane16);
        curB.u[0] = ldtap(tpb, __shfl(B.my.o0, src, 64) + lane16);
        curB.u[1] = ldtap(tpb, __shfl(B.my.o1, src, 64) + lane16);
        curB.u[2] = ldtap(tpb, __shfl(B.my.o2, src, 64) + lane16);
        curB.u[3] = ldtap(tpb, __shfl(B.my.o3, src, 64) + lane16);
        curB.u[4] = ldtap(tpb, __shfl(B.my.o4, src, 64) + lane16);
        curB.u[5] = ldtap(tpb, __shfl(B.my.o5, src, 64) + lane16);
    }
#pragma unroll
    for (int s = 0; s < SS; ++s) {
        if (s < SS - 1) {
            int src = base | (s + 1);
            nxtA.u[0] = ldtap(tpb, __shfl(A.my.o0, src, 64) + lane16);
            nxtA.u[1] = ldtap(tpb, __shfl(A.my.o1, src, 64) + lane16);
            nxtA.u[2] = ldtap(tpb, __shfl(A.my.o2, src, 64) + lane16);
            nxtA.u[3] = ldtap(tpb, __shfl(A.my.o3, src, 64) + lane16);
            nxtA.u[4] = ldtap(tpb, __shfl(A.my.o4, src, 64) + lane16);
            nxtA.u[5] = ldtap(tpb, __shfl(A.my.o5, src, 64) + lane16);
            nxtB.u[0] = ldtap(tpb, __shfl(B.my.o0, src, 64) + lane16);
            nxtB.u[1] = ldtap(tpb, __shfl(B.my.o1, src, 64) + lane16);
            nxtB.u[2] = ldtap(tpb, __shfl(B.my.o2, src, 64) + lane16);
            nxtB.u[3] = ldtap(tpb, __shfl(B.my.o3, src, 64) + lane16);
            nxtB.u[4] = ldtap(tpb, __shfl(B.my.o4, src, 64) + lane16);
            nxtB.u[5] = ldtap(tpb, __shfl(B.my.o5, src, 64) + lane16);
        }
        int src = base | s;
        eval_rowp(A.wa, curA.u[0], (unsigned)__shfl((int)A.m0, src, 64));
        eval_rowp(A.wa, curA.u[1], (unsigned)__shfl((int)A.m1, src, 64));
        eval_rowp(A.wa, curA.u[2], (unsigned)__shfl((int)A.m2, src, 64));
        eval_rowp(A.wa, curA.u[3], (unsigned)__shfl((int)A.m3, src, 64));
        eval_rowp(A.wa, curA.u[4], (unsigned)__shfl((int)A.m4, src, 64));
        eval_rowp(A.wa, curA.u[5], (unsigned)__shfl((int)A.m5, src, 64));
        eval_rowp(B.wa, curB.u[0], (unsigned)__shfl((int)B.m0, src, 64));
        eval_rowp(B.wa, curB.u[1], (unsigned)__shfl((int)B.m1, src, 64));
        eval_rowp(B.wa, curB.u[2], (unsigned)__shfl((int)B.m2, src, 64));
        eval_rowp(B.wa, curB.u[3], (unsigned)__shfl((int)B.m3, src, 64));
        eval_rowp(B.wa, curB.u[4], (unsigned)__shfl((int)B.m4, src, 64));
        eval_rowp(B.wa, curB.u[5], (unsigned)__shfl((int)B.m5, src, 64));
        if (s < SS - 1) { curA = nxtA; curB = nxtB; }
    }

    // ---- out = wa @ (W_v@W_out) + wsum*(b_v@W_out) + b_out + feature ----
    f4 oA, oB;
    {
        v2f bo  = {sbout[(lane << 2) + 0], sbout[(lane << 2) + 1]};
        v2f bo2 = {sbout[(lane << 2) + 2], sbout[(lane << 2) + 3]};
        v2f bv2 = {sbvw[(lane << 2) + 0], sbvw[(lane << 2) + 1]};
        v2f bv3 = {sbvw[(lane << 2) + 2], sbvw[(lane << 2) + 3]};
        v2f wsA = {A.wsum, A.wsum};
        v2f wsB = {B.wsum, B.wsum};
        oA.lo = __builtin_elementwise_fma(wsA, bv2, bo)  + A.feat.lo;
        oA.hi = __builtin_elementwise_fma(wsA, bv3, bo2) + A.feat.hi;
        oB.lo = __builtin_elementwise_fma(wsB, bv2, bo)  + B.feat.lo;
        oB.hi = __builtin_elementwise_fma(wsB, bv3, bo2) + B.feat.hi;
    }
    // wa packed as f16 pairs: safe (final non-amplified linear, err ~0.005)
    unsigned pkLoA = pack2(A.wa.lo.x, A.wa.lo.y);
    unsigned pkHiA = pack2(A.wa.hi.x, A.wa.hi.y);
    unsigned pkLoB = pack2(B.wa.lo.x, B.wa.lo.y);
    unsigned pkHiB = pack2(B.wa.hi.x, B.wa.hi.y);
#pragma unroll
    for (int k2 = 0; k2 < 16; ++k2) {
        int src = base | (k2 >> 1);
        unsigned wbA = (unsigned)__shfl((int)((k2 & 1) ? pkHiA : pkLoA), src, 64);
        unsigned wbB = (unsigned)__shfl((int)((k2 & 1) ? pkHiB : pkLoB), src, 64);
        const uint4 wv = *(const uint4*)&sWc2h[k2][lane << 2];
        dot2_4(oA, wv, wbA);
        dot2_4(oB, wv, wbB);
    }

    if (qiA < NS) {
        float* dst = out + ((size_t)b * NS + qiA) * 32 + (lane << 2);
        *(float4*)dst = make_float4(oA.lo.x, oA.lo.y, oA.hi.x, oA.hi.y);
    }
    if (qiB < NS) {
        float* dst = out + ((size_t)b * NS + qiB) * 32 + (lane << 2);
        *(float4*)dst = make_float4(oB.lo.x, oB.lo.y, oB.hi.x, oB.hi.y);
    }
}

extern "C" void kernel_launch(void* const* d_in, const int* in_sizes, int n_in,
                              void* d_out, int out_size, void* d_ws, size_t ws_size,
                              hipStream_t stream) {
    const float* qp   = (const float*)d_in[0];
    const float* cxz  = (const float*)d_in[1];
    const float* cxy  = (const float*)d_in[2];
    const float* cyz  = (const float*)d_in[3];
    const float* Woff = (const float*)d_in[4];
    const float* boff = (const float*)d_in[5];
    const float* Ww   = (const float*)d_in[6];
    const float* bw   = (const float*)d_in[7];
    const float* Wv   = (const float*)d_in[8];
    const float* bv   = (const float*)d_in[9];
    const float* Wout = (const float*)d_in[10];
    const float* bout = (const float*)d_in[11];
    float* out = (float*)d_out;

    unsigned* tp = (unsigned*)d_ws;
    float* Wc  = (float*)((char*)d_ws + (size_t)BS * 3 * RR * RR * CCH * 4);
    float* bvw = Wc + 1024;

    prep<<<BS * 3 * RR + 4, 256, 0, stream>>>(cxz, cxy, cyz, Wv, bv, Wout, tp, Wc, bvw);
    // even blockIdx -> batch 0, odd -> batch 1 (round-robin block->XCD dispatch
    // biases each XCD toward one batch's planes).
    int blocks_per_batch = (NS + 63) / 64;   // 64 queries per 256-thread block
    eda_main<<<2 * blocks_per_batch, 256, 0, stream>>>(qp, tp, Woff, boff, Ww, bw,
                                                       Wc, bvw, bout, out);
}

// Round 9
// 129.713 us; speedup vs baseline: 1.0508x; 1.0508x over previous
//
#include <hip/hip_runtime.h>
#include <hip/hip_fp16.h>

#define BS 2
#define NS 50000
#define CCH 32
#define RR 128
#define SS 8

typedef float v2f __attribute__((ext_vector_type(2)));
typedef _Float16 h2 __attribute__((ext_vector_type(2)));

#if __has_builtin(__builtin_amdgcn_fdot2)
#define HAVE_DOT2 1
#else
#define HAVE_DOT2 0
#endif

// ws layout (pair-replicated fp16 planes; best-measured tap format):
//   tp : BS*3*RR*RR blocks of 128 B:
//        block (b,pl,y,x) holds channels c=0..31 interleaved {col x, col x+1}:
//        uint32 #c = half(src[c][y][x]) | half(src[c][y][min(x+1,127)])<<16
//        = 12,582,912 B
//   Wc : 1024 floats  (W_v @ W_out)
//   bvw: 32 floats    (b_v @ W_out)
//
// SESSION NOTES (convergence): eda_main is pinned at ~47-49 us across every
// structural variant tried (VALU cuts, VMEM cuts, L2-residency, DS-op halving,
// prefetch depth 2, dual-query ILP). No pipe exceeds ~50%; the kernel is
// balanced across VALU/DS/VMEM-latency. Total dur ~130 us of which ~71 us is
// fixed harness reset (268 MB ws poison fill at HBM-write ceiling + tiny
// dispatches). This file is the best fill-noise-adjusted configuration.
// Numerics constraints learned: cat-matmul MUST stay f32 (offsets are
// gradient-amplified; fp16 there failed absmax in R4). Out-matmul fp16 is safe.

__device__ __forceinline__ unsigned pk_rn(float a, float b) {
    unsigned h0 = __half_as_ushort(__float2half(a));
    unsigned h1 = __half_as_ushort(__float2half(b));
    return h0 | (h1 << 16);
}

// blocks 0..767: transpose+convert+replicate one (b,pl,y) row via LDS.
// blocks 768..771: compute Wc = Wv@Wout and bvw = bv@Wout.
__global__ __launch_bounds__(256)
void prep(const float* __restrict__ cxz,
          const float* __restrict__ cxy,
          const float* __restrict__ cyz,
          const float* __restrict__ Wv, const float* __restrict__ bv,
          const float* __restrict__ Wout,
          unsigned* __restrict__ tp, float* __restrict__ Wc,
          float* __restrict__ bvw) {
    __shared__ float lds[32 * 129];
    int tid = threadIdx.x;
    int row = blockIdx.x;
    if (row < BS * 3 * RR) {
        int y  = row & 127;
        int pl = (row >> 7) % 3;
        int b  = row / 384;
        const float* src = (pl == 0) ? cxz : ((pl == 1) ? cxy : cyz);
        const float* sp = src + (((size_t)(b * CCH)) << 14) + (y << 7);
        int c = tid >> 3, xq = tid & 7;
        const float4* s4 = (const float4*)(sp + ((size_t)c << 14));
#pragma unroll
        for (int k = 0; k < 4; ++k) {
            float4 v = s4[xq + 8 * k];
            int x = (xq + 8 * k) << 2;
            lds[c * 129 + x + 0] = v.x;
            lds[c * 129 + x + 1] = v.y;
            lds[c * 129 + x + 2] = v.z;
            lds[c * 129 + x + 3] = v.w;
        }
        __syncthreads();
        uint4* dst = (uint4*)(tp + ((size_t)row << 12));
#pragma unroll
        for (int i = 0; i < 4; ++i) {
            int j = tid + 256 * i;          // uint4 index 0..1023
            int x  = j >> 3;
            int c0 = (j & 7) << 2;          // channels c0..c0+3 at column x
            int x1 = min(x + 1, 127);
            uint4 o;
            o.x = pk_rn(lds[(c0 + 0) * 129 + x], lds[(c0 + 0) * 129 + x1]);
            o.y = pk_rn(lds[(c0 + 1) * 129 + x], lds[(c0 + 1) * 129 + x1]);
            o.z = pk_rn(lds[(c0 + 2) * 129 + x], lds[(c0 + 2) * 129 + x1]);
            o.w = pk_rn(lds[(c0 + 3) * 129 + x], lds[(c0 + 3) * 129 + x1]);
            dst[j] = o;
        }
    } else {
        int t = (row - BS * 3 * RR) * 256 + tid;    // 0..1023
        int c = t >> 5, j = t & 31;
        float acc = 0.f;
#pragma unroll
        for (int k = 0; k < 32; ++k) acc += Wv[c * 32 + k] * Wout[k * 32 + j];
        Wc[t] = acc;
        if (t < 32) {
            float a2 = 0.f;
#pragma unroll
            for (int k = 0; k < 32; ++k) a2 += bv[k] * Wout[k * 32 + t];
            bvw[t] = a2;
        }
    }
}

// ---- main kernel: 8 lanes/query, lane owns channels 4l..4l+3.
// Plane base tpb is WAVE-UNIFORM (char*); all tap addressing via 32-bit BYTE
// offsets (+ lane*16): global_load_dwordx4 v,voff,s[base].
// Byte offsets: plane stride 1<<21, y stride 1<<14, x stride 1<<7.

struct f4 { v2f lo, hi; };   // 4 channels

struct Coord {
    int o0, o1, o2, o3, o4, o5;
    float wc0, wc1, wr1, wr2;
};

__device__ __forceinline__ Coord coord(float p0, float p1, float p2) {
    Coord c;
    float x0c = fminf(fmaxf(p0, 0.f), 1.f) * 127.f;
    int i0 = min((int)x0c, 126);
    c.wc0 = x0c - (float)i0;
    float x1c = fminf(fmaxf(p1, 0.f), 1.f) * 127.f;
    int i1 = min((int)x1c, 126);
    c.wc1 = x1c - (float)i1;
    float f1 = floorf(x1c);
    int r10 = (int)f1, r11 = min(r10 + 1, 127);
    c.wr1 = x1c - f1;
    float x2c = fminf(fmaxf(p2, 0.f), 1.f) * 127.f;
    float f2 = floorf(x2c);
    int r20 = (int)f2, r21 = min(r20 + 1, 127);
    c.wr2 = x2c - f2;
    int c0 = i0 << 7, c1 = i1 << 7;
    c.o0 = (r20 << 14) + c0;
    c.o1 = (r21 << 14) + c0;
    c.o2 = (1 << 21) + (r10 << 14) + c0;
    c.o3 = (1 << 21) + (r11 << 14) + c0;
    c.o4 = (2 << 21) + (r20 << 14) + c1;
    c.o5 = (2 << 21) + (r21 << 14) + c1;
    return c;
}

__device__ __forceinline__ uint4 ldtap(const char* __restrict__ tpb, int off) {
    return *(const uint4*)(tpb + off);
}

struct SampB { uint4 u[6]; };   // in-flight tap data (24 VGPR)

__device__ __forceinline__ unsigned pack2(float a, float b) {
#if HAVE_DOT2
    return __builtin_bit_cast(unsigned, __builtin_amdgcn_cvt_pkrtz(a, b));
#else
    __half2 h = __floats2half2_rn(a, b);
    return __builtin_bit_cast(unsigned, h);
#endif
}

#if HAVE_DOT2
__device__ __forceinline__ void eval_row(f4& acc, uint4 u, h2 w) {
    acc.lo.x = __builtin_amdgcn_fdot2(__builtin_bit_cast(h2, u.x), w, acc.lo.x, false);
    acc.lo.y = __builtin_amdgcn_fdot2(__builtin_bit_cast(h2, u.y), w, acc.lo.y, false);
    acc.hi.x = __builtin_amdgcn_fdot2(__builtin_bit_cast(h2, u.z), w, acc.hi.x, false);
    acc.hi.y = __builtin_amdgcn_fdot2(__builtin_bit_cast(h2, u.w), w, acc.hi.y, false);
}

__device__ __forceinline__ void eval_plane(f4& acc, uint4 ua, uint4 ub,
                                           float wx, float wy) {
    float wB1 = wx * wy;          // (x1,y1)
    float wB0 = wx - wB1;         // (x1,y0)
    float wA1 = wy - wB1;         // (x0,y1)
    float wA0 = 1.f - wx - wA1;   // (x0,y0)
    h2 w0 = __builtin_bit_cast(h2, __builtin_amdgcn_cvt_pkrtz(wA0, wB0));
    h2 w1 = __builtin_bit_cast(h2, __builtin_amdgcn_cvt_pkrtz(wA1, wB1));
    eval_row(acc, ua, w0);
    eval_row(acc, ub, w1);
}

__device__ __forceinline__ void eval_rowp(f4& acc, uint4 u, unsigned pw) {
    eval_row(acc, u, __builtin_bit_cast(h2, pw));
}

__device__ __forceinline__ void dot2_4(f4& acc, uint4 wv, unsigned pw) {
    h2 w = __builtin_bit_cast(h2, pw);
    acc.lo.x = __builtin_amdgcn_fdot2(__builtin_bit_cast(h2, wv.x), w, acc.lo.x, false);
    acc.lo.y = __builtin_amdgcn_fdot2(__builtin_bit_cast(h2, wv.y), w, acc.lo.y, false);
    acc.hi.x = __builtin_amdgcn_fdot2(__builtin_bit_cast(h2, wv.z), w, acc.hi.x, false);
    acc.hi.y = __builtin_amdgcn_fdot2(__builtin_bit_cast(h2, wv.w), w, acc.hi.y, false);
}
#else
__device__ __forceinline__ void eval_row(f4& acc, uint4 u, float wA, float wB) {
    __half2 h0 = __builtin_bit_cast(__half2, u.x);
    __half2 h1 = __builtin_bit_cast(__half2, u.y);
    __half2 h2_ = __builtin_bit_cast(__half2, u.z);
    __half2 h3 = __builtin_bit_cast(__half2, u.w);
    acc.lo.x = fmaf(__half2float(h0.y), wB, fmaf(__half2float(h0.x), wA, acc.lo.x));
    acc.lo.y = fmaf(__half2float(h1.y), wB, fmaf(__half2float(h1.x), wA, acc.lo.y));
    acc.hi.x = fmaf(__half2float(h2_.y), wB, fmaf(__half2float(h2_.x), wA, acc.hi.x));
    acc.hi.y = fmaf(__half2float(h3.y), wB, fmaf(__half2float(h3.x), wA, acc.hi.y));
}

__device__ __forceinline__ void eval_plane(f4& acc, uint4 ua, uint4 ub,
                                           float wx, float wy) {
    float wB1 = wx * wy;
    float wB0 = wx - wB1;
    float wA1 = wy - wB1;
    float wA0 = 1.f - wx - wA1;
    eval_row(acc, ua, wA0, wB0);
    eval_row(acc, ub, wA1, wB1);
}

__device__ __forceinline__ void eval_rowp(f4& acc, uint4 u, unsigned pw) {
    __half2 hw = __builtin_bit_cast(__half2, pw);
    eval_row(acc, u, __half2float(hw.x), __half2float(hw.y));
}

__device__ __forceinline__ void dot2_4(f4& acc, uint4 wv, unsigned pw) {
    __half2 hw = __builtin_bit_cast(__half2, pw);
    float a0 = __half2float(hw.x), a1 = __half2float(hw.y);
    __half2 w0 = __builtin_bit_cast(__half2, wv.x);
    __half2 w1 = __builtin_bit_cast(__half2, wv.y);
    __half2 w2_ = __builtin_bit_cast(__half2, wv.z);
    __half2 w3 = __builtin_bit_cast(__half2, wv.w);
    acc.lo.x = fmaf(__half2float(w0.y), a1, fmaf(__half2float(w0.x), a0, acc.lo.x));
    acc.lo.y = fmaf(__half2float(w1.y), a1, fmaf(__half2float(w1.x), a0, acc.lo.y));
    acc.hi.x = fmaf(__half2float(w2_.y), a1, fmaf(__half2float(w2_.x), a0, acc.hi.x));
    acc.hi.y = fmaf(__half2float(w3.y), a1, fmaf(__half2float(w3.x), a0, acc.hi.y));
}
#endif

// element idx (0..3 within lane) of f4; compile-time idx.
#define GETE(v, idx) (((idx) & 2) ? (((idx) & 1) ? (v).hi.y : (v).hi.x) \
                                  : (((idx) & 1) ? (v).lo.y : (v).lo.x))
// broadcast channel idx (0..31) across the 8-lane query group (base = tid & 56).
#define GETC(v, idx) __shfl(GETE(v, idx), base | ((idx) >> 2), 64)

__global__ __launch_bounds__(256)
void eda_main(const float* __restrict__ qp, const unsigned* __restrict__ tp,
              const float* __restrict__ Woff, const float* __restrict__ boff,
              const float* __restrict__ Ww, const float* __restrict__ bw,
              const float* __restrict__ Wc, const float* __restrict__ bvw,
              const float* __restrict__ bout, float* __restrict__ out) {
    // sWcat is COLUMN-PERMUTED, kept in F32 (offsets are gradient-amplified;
    // fp16 here failed absmax in R4):
    //   col 4l+e = (e<3) ? W_off col (3l+e) : W_w col l
    // => after cat-matmul, lane l holds (dx,dy,dz,w) of aux sample s=l directly.
    __shared__ float    sWcat[32][32];
    __shared__ unsigned sWc2h[16][32];  // f16-pair packed Wc: [k2][j] = (Wc[2k2][j], Wc[2k2+1][j])
    __shared__ float sbcat[32];         // permuted like sWcat cols
    __shared__ float sbvw[32];
    __shared__ float sbout[32];

    int tid = threadIdx.x;
    int lane = tid & 7;
    int lane16 = lane << 4;
    int base = tid & 56;                          // query-group base within wave
    int b  = blockIdx.x & 1;                      // XCD-parity batch split
    int qi = (blockIdx.x >> 1) * 32 + (tid >> 3); // query within batch
    int qq = min(qi, NS - 1);

    const float* p = qp + ((size_t)b * NS + qq) * 3;
    float p0 = p[0], p1 = p[1], p2 = p[2];

    // wave-uniform plane base (batch select); taps use 32-bit byte offsets
    const char* tpb = (const char*)tp + ((size_t)(b * 3) << 21);

    // ---- issue feature tap loads early; they fly during LDS weight staging ----
    Coord fc = coord(p0, p1, p2);
    SampB fs;
    fs.u[0] = ldtap(tpb, fc.o0 + lane16); fs.u[1] = ldtap(tpb, fc.o1 + lane16);
    fs.u[2] = ldtap(tpb, fc.o2 + lane16); fs.u[3] = ldtap(tpb, fc.o3 + lane16);
    fs.u[4] = ldtap(tpb, fc.o4 + lane16); fs.u[5] = ldtap(tpb, fc.o5 + lane16);

    for (int i = tid; i < 1024; i += 256) {
        int k = i >> 5, j = i & 31, l2 = j >> 2, e = j & 3;
        sWcat[k][j] = (e < 3) ? Woff[k * 24 + 3 * l2 + e] : Ww[k * 8 + l2];
    }
    {
        int k2 = tid >> 5, j = tid & 31;
        sWc2h[k2][j]     = pk_rn(Wc[k2 * 64 + j],        Wc[k2 * 64 + 32 + j]);
        sWc2h[k2 + 8][j] = pk_rn(Wc[(k2 + 8) * 64 + j],  Wc[(k2 + 8) * 64 + 32 + j]);
    }
    if (tid < 32) {
        int l2 = tid >> 2, e = tid & 3;
        sbcat[tid] = (e < 3) ? boff[3 * l2 + e] : bw[l2];
        sbvw[tid]  = bvw[tid];
        sbout[tid] = bout[tid];
    }
    __syncthreads();

    // ---- feature ----
    f4 feat; feat.lo = (v2f){0.f, 0.f}; feat.hi = (v2f){0.f, 0.f};
    eval_plane(feat, fs.u[0], fs.u[1], fc.wc0, fc.wr2);   // XZ
    eval_plane(feat, fs.u[2], fs.u[3], fc.wc0, fc.wr1);   // XY
    eval_plane(feat, fs.u[4], fs.u[5], fc.wc1, fc.wr2);   // YZ

    // ---- cat = feature @ [W_off | W_w] (permuted cols, F32) + bias ----
    f4 cat;
    cat.lo.x = sbcat[(lane << 2) + 0]; cat.lo.y = sbcat[(lane << 2) + 1];
    cat.hi.x = sbcat[(lane << 2) + 2]; cat.hi.y = sbcat[(lane << 2) + 3];
#pragma unroll
    for (int k = 0; k < 32; ++k) {
        float fcv = GETC(feat, k);
        const v2f* wp = (const v2f*)&sWcat[k][lane << 2];
        v2f fc2 = {fcv, fcv};
        cat.lo = __builtin_elementwise_fma(fc2, wp[0], cat.lo);
        cat.hi = __builtin_elementwise_fma(fc2, wp[1], cat.hi);
    }

    // ---- per-lane precompute for MY sample (s = lane): byte offsets +
    //      wt-premultiplied packed corner weights ----
    Coord my = coord(p0 + cat.lo.x, p1 + cat.lo.y, p2 + cat.hi.x);
    float wt_my = cat.hi.y;
    unsigned m0, m1, m2, m3, m4, m5;
    { float wB1 = my.wc0 * my.wr2, wB0 = my.wc0 - wB1, wA1 = my.wr2 - wB1, wA0 = 1.f - my.wc0 - wA1;
      m0 = pack2(wA0 * wt_my, wB0 * wt_my); m1 = pack2(wA1 * wt_my, wB1 * wt_my); }  // XZ
    { float wB1 = my.wc0 * my.wr1, wB0 = my.wc0 - wB1, wA1 = my.wr1 - wB1, wA0 = 1.f - my.wc0 - wA1;
      m2 = pack2(wA0 * wt_my, wB0 * wt_my); m3 = pack2(wA1 * wt_my, wB1 * wt_my); }  // XY
    { float wB1 = my.wc1 * my.wr2, wB0 = my.wc1 - wB1, wA1 = my.wr2 - wB1, wA0 = 1.f - my.wc1 - wA1;
      m4 = pack2(wA0 * wt_my, wB0 * wt_my); m5 = pack2(wA1 * wt_my, wB1 * wt_my); }  // YZ

    // wsum = sum of group's 8 sample weights (butterfly within 8-lane group)
    float wsum = wt_my;
    wsum += __shfl_xor(wsum, 1, 64);
    wsum += __shfl_xor(wsum, 2, 64);
    wsum += __shfl_xor(wsum, 4, 64);

    // ---- s-loop, depth-1 prefetch; fdot2 accumulates straight into wa ----
    f4 wa; wa.lo = (v2f){0.f, 0.f}; wa.hi = (v2f){0.f, 0.f};
    SampB cur, nxt;
    {
        int src = base;        // s = 0
        cur.u[0] = ldtap(tpb, __shfl(my.o0, src, 64) + lane16);
        cur.u[1] = ldtap(tpb, __shfl(my.o1, src, 64) + lane16);
        cur.u[2] = ldtap(tpb, __shfl(my.o2, src, 64) + lane16);
        cur.u[3] = ldtap(tpb, __shfl(my.o3, src, 64) + lane16);
        cur.u[4] = ldtap(tpb, __shfl(my.o4, src, 64) + lane16);
        cur.u[5] = ldtap(tpb, __shfl(my.o5, src, 64) + lane16);
    }
#pragma unroll
    for (int s = 0; s < SS; ++s) {
        if (s < SS - 1) {
            int src = base | (s + 1);
            nxt.u[0] = ldtap(tpb, __shfl(my.o0, src, 64) + lane16);
            nxt.u[1] = ldtap(tpb, __shfl(my.o1, src, 64) + lane16);
            nxt.u[2] = ldtap(tpb, __shfl(my.o2, src, 64) + lane16);
            nxt.u[3] = ldtap(tpb, __shfl(my.o3, src, 64) + lane16);
            nxt.u[4] = ldtap(tpb, __shfl(my.o4, src, 64) + lane16);
            nxt.u[5] = ldtap(tpb, __shfl(my.o5, src, 64) + lane16);
        }
        int src = base | s;
        eval_rowp(wa, cur.u[0], (unsigned)__shfl((int)m0, src, 64));
        eval_rowp(wa, cur.u[1], (unsigned)__shfl((int)m1, src, 64));
        eval_rowp(wa, cur.u[2], (unsigned)__shfl((int)m2, src, 64));
        eval_rowp(wa, cur.u[3], (unsigned)__shfl((int)m3, src, 64));
        eval_rowp(wa, cur.u[4], (unsigned)__shfl((int)m4, src, 64));
        eval_rowp(wa, cur.u[5], (unsigned)__shfl((int)m5, src, 64));
        if (s < SS - 1) cur = nxt;
    }

    // ---- out = wa @ (W_v@W_out) + wsum*(b_v@W_out) + b_out + feature ----
    f4 o;
    v2f ws2 = {wsum, wsum};
    {
        v2f bo  = {sbout[(lane << 2) + 0], sbout[(lane << 2) + 1]};
        v2f bv2 = {sbvw[(lane << 2) + 0], sbvw[(lane << 2) + 1]};
        o.lo = __builtin_elementwise_fma(ws2, bv2, bo) + feat.lo;
        v2f bo2 = {sbout[(lane << 2) + 2], sbout[(lane << 2) + 3]};
        v2f bv3 = {sbvw[(lane << 2) + 2], sbvw[(lane << 2) + 3]};
        o.hi = __builtin_elementwise_fma(ws2, bv3, bo2) + feat.hi;
    }
    // wa packed as f16 pairs: safe (final non-amplified linear, err ~0.005)
    unsigned pkLo = pack2(wa.lo.x, wa.lo.y);   // channels 4l, 4l+1
    unsigned pkHi = pack2(wa.hi.x, wa.hi.y);   // channels 4l+2, 4l+3
#pragma unroll
    for (int k2 = 0; k2 < 16; ++k2) {
        unsigned wb = (unsigned)__shfl((int)((k2 & 1) ? pkHi : pkLo), base | (k2 >> 1), 64);
        const uint4 wv = *(const uint4*)&sWc2h[k2][lane << 2];
        dot2_4(o, wv, wb);
    }

    if (qi < NS) {
        float* dst = out + ((size_t)b * NS + qi) * 32 + (lane << 2);
        *(float4*)dst = make_float4(o.lo.x, o.lo.y, o.hi.x, o.hi.y);
    }
}

extern "C" void kernel_launch(void* const* d_in, const int* in_sizes, int n_in,
                              void* d_out, int out_size, void* d_ws, size_t ws_size,
                              hipStream_t stream) {
    const float* qp   = (const float*)d_in[0];
    const float* cxz  = (const float*)d_in[1];
    const float* cxy  = (const float*)d_in[2];
    const float* cyz  = (const float*)d_in[3];
    const float* Woff = (const float*)d_in[4];
    const float* boff = (const float*)d_in[5];
    const float* Ww   = (const float*)d_in[6];
    const float* bw   = (const float*)d_in[7];
    const float* Wv   = (const float*)d_in[8];
    const float* bv   = (const float*)d_in[9];
    const float* Wout = (const float*)d_in[10];
    const float* bout = (const float*)d_in[11];
    float* out = (float*)d_out;

    unsigned* tp = (unsigned*)d_ws;
    float* Wc  = (float*)((char*)d_ws + (size_t)BS * 3 * RR * RR * CCH * 4);
    float* bvw = Wc + 1024;

    prep<<<BS * 3 * RR + 4, 256, 0, stream>>>(cxz, cxy, cyz, Wv, bv, Wout, tp, Wc, bvw);
    // even blockIdx -> batch 0, odd -> batch 1 (round-robin block->XCD dispatch
    // biases each XCD toward one batch's planes).
    int blocks_per_batch = (NS + 31) / 32;   // 32 queries per 256-thread block
    eda_main<<<2 * blocks_per_batch, 256, 0, stream>>>(qp, tp, Woff, boff, Ww, bw,
                                                       Wc, bvw, bout, out);
}